// Round 3
// baseline (38427.542 us; speedup 1.0000x reference)
//
#include <hip/hip_runtime.h>
#include <hip/hip_cooperative_groups.h>

namespace cg = cooperative_groups;

constexpr int Bb = 32;     // batch
constexpr int Tt = 512;    // time
constexpr int KI = 1024;   // input dim
constexpr int HH = 1024;   // hidden dim

// ws layout (float4 units):
//   xT4  : [T][KI/4][B]   = 512*256*32 = 4,194,304 float4  (inputs transposed)
//   hbuf4: [T+1][HH/4][B] = 513*256*32 = 4,202,496 float4  (h history; slot 0 = h0)
// total 134,348,800 bytes

// ---------------- prep: transpose inputs and h0 into lane-coalesced layout ----------------
__global__ void prep_kernel(const float4* __restrict__ in4,
                            const float* __restrict__ h0,
                            float4* __restrict__ xT4,
                            float4* __restrict__ hbuf4)
{
    int idx = blockIdx.x * 256 + threadIdx.x;
    constexpr int NX = Bb * Tt * (KI / 4);          // 4,194,304
    if (idx < NX) {
        int kq = idx & 255;
        int t  = (idx >> 8) & 511;
        int b  = idx >> 17;
        xT4[((size_t)t * 256 + kq) * 32 + b] = in4[idx];
    } else {
        int r = idx - NX;
        if (r < (HH / 4) * Bb) {                    // 8192
            int b  = r & 31;
            int jq = r >> 5;
            hbuf4[(size_t)jq * 32 + b] = *(const float4*)(h0 + (size_t)b * HH + jq * 4);
        }
    }
}

// ---------------- final: hbuf (transposed h history) -> logits [B][T][H] ----------------
__global__ void logits_kernel(const float4* __restrict__ hbuf4, float4* __restrict__ out4)
{
    int idx = blockIdx.x * 256 + threadIdx.x;       // (b*T + t)*256 + j4
    constexpr int N = Bb * Tt * (HH / 4);
    if (idx >= N) return;
    int j4 = idx & 255;
    int t  = (idx >> 8) & 511;
    int b  = idx >> 17;
    out4[idx] = hbuf4[((size_t)(t + 1) * 256 + j4) * 32 + b];
}

// 32-iter dot fragment: 1 x-load + 8 weight-row loads -> 32 FMAs per iter.
// wr[] indexed only by unrolled r (compile-time) -> stays in registers.
template<int STRIDE>
__device__ __forceinline__ void dot32(const float4* __restrict__ xp,
                                      const float4* const* __restrict__ wr,
                                      float4 acc[8])
{
#pragma unroll 4
    for (int i = 0; i < 32; ++i) {
        float4 xv = xp[(size_t)i * STRIDE];
#pragma unroll
        for (int r = 0; r < 8; ++r) {
            float4 wv = wr[r][i];
            acc[r].x = fmaf(wv.x, xv.x, acc[r].x);
            acc[r].y = fmaf(wv.y, xv.y, acc[r].y);
            acc[r].z = fmaf(wv.z, xv.z, acc[r].z);
            acc[r].w = fmaf(wv.w, xv.w, acc[r].w);
        }
    }
}

// ---------------- persistent LSTM ----------------
// 256 blocks x 512 threads (8 waves = 2/SIMD). Block bid owns hidden units
// j in [bid*4, bid*4+4) -> 16 gate-rows. Wave w owns float4-k window
// [w*32, w*32+32) of BOTH the x-dot (K=1024) and h-dot (H=1024); lanes carry
// batch b (dup across halves); each half register-tiles 8 gate-rows.
// Software pipeline: xdot(t+1) executes between the h-write and grid.sync,
// filling the barrier shadow; hdot(t) runs right after the sync releases.
// c lives in combiner registers (tid<128, thread=(b,j)) for all 512 steps.
template<bool GATHER>
__global__ __launch_bounds__(512, 2)
void lstm_seq(const float* __restrict__ inputs,
              const float* __restrict__ h0,
              const float* __restrict__ c0,
              const float* __restrict__ W_ih,
              const float* __restrict__ b_ih,
              const float* __restrict__ W_hh,
              const float* __restrict__ b_hh,
              const float4* __restrict__ xT4,
              float4* __restrict__ hbuf4,
              float* __restrict__ out)
{
    cg::grid_group grid = cg::this_grid();
    const int tid  = threadIdx.x;
    const int bid  = blockIdx.x;
    const int w    = tid >> 6;           // wave 0..7 -> k-window
    const int lane = tid & 63;
    const int b    = lane & 31;          // batch on lanes (coalesced x/h reads)
    const int half = lane >> 5;          // half-wave -> row group
    const int j0   = bid * 4;

    // this thread's 8 gate-rows: rr = half*8 + r; global row = g*HH + j0 + jl
    // (g = rr&3: 0=i,1=f,2=o,3=g per reference row order; jl = rr>>2)
    const float4* wx[8];
    const float4* wh[8];
#pragma unroll
    for (int r = 0; r < 8; ++r) {
        int rr  = half * 8 + r;
        int row = (rr & 3) * HH + j0 + (rr >> 2);
        wx[r] = (const float4*)(W_ih + (size_t)row * KI) + w * 32;
        wh[r] = (const float4*)(W_hh + (size_t)row * HH) + w * 32;
    }

    __shared__ float part[16][8][32];    // [rr][wave][b]; 16 KB

    // combiner: thread tid<128 owns (b=tid>>2, j=j0+(tid&3)); c never leaves regs
    const int cb = tid >> 2;
    const int cj = tid & 3;
    float c_reg = 0.f;
    float bsum[4] = {0.f, 0.f, 0.f, 0.f};
    if (tid < 128) {
        c_reg = c0[(size_t)cb * HH + j0 + cj];
#pragma unroll
        for (int g = 0; g < 4; ++g) {
            int row = g * HH + j0 + cj;
            bsum[g] = b_ih[row] + b_hh[row];
        }
    }

    float* logits = out;
    float* h_f = out + (size_t)Bb * Tt * HH;
    float* c_f = h_f + (size_t)Bb * HH;

    // prologue: xacc = xdot(t=0)
    float4 xacc[8];
#pragma unroll
    for (int r = 0; r < 8; ++r) xacc[r] = make_float4(0.f, 0.f, 0.f, 0.f);
    if (!GATHER) {
        dot32<32>(xT4 + (size_t)0 * 8192 + w * 1024 + b, wx, xacc);
    } else {
        dot32<1>((const float4*)(inputs + ((size_t)b * Tt + 0) * KI) + w * 32, wx, xacc);
    }

    for (int t = 0; t < Tt; ++t) {
        // h-dot for step t (h_{t-1} lives in slot t / logits row t-1)
        float4 hacc[8];
#pragma unroll
        for (int r = 0; r < 8; ++r) hacc[r] = make_float4(0.f, 0.f, 0.f, 0.f);
        if (!GATHER) {
            dot32<32>(hbuf4 + (size_t)t * 8192 + w * 1024 + b, wh, hacc);
        } else {
            const float4* hp = (t == 0)
                ? (const float4*)(h0 + (size_t)b * HH) + w * 32
                : (const float4*)(logits + ((size_t)b * Tt + (t - 1)) * HH) + w * 32;
            dot32<1>(hp, wh, hacc);
        }

        // publish x+h partials
#pragma unroll
        for (int r = 0; r < 8; ++r) {
            float s = (hacc[r].x + hacc[r].y) + (hacc[r].z + hacc[r].w)
                    + (xacc[r].x + xacc[r].y) + (xacc[r].z + xacc[r].w);
            part[half * 8 + r][w][b] = s;
        }
        __syncthreads();

        if (tid < 128) {
            float pr[4];
#pragma unroll
            for (int g = 0; g < 4; ++g) {
                float s = bsum[g];
#pragma unroll
                for (int ww = 0; ww < 8; ++ww) s += part[cj * 4 + g][ww][cb];
                pr[g] = s;
            }
            float ig = 1.f / (1.f + expf(-pr[0]));
            float fg = 1.f / (1.f + expf(-pr[1]));
            float og = 1.f / (1.f + expf(-pr[2]));
            float gg = tanhf(pr[3]);
            c_reg = c_reg * fg + ig * gg;
            float hv = og * tanhf(c_reg);
            if (!GATHER) {
                // 128 threads write 128 consecutive floats of hbuf slot t+1, row jq=bid
                ((float*)hbuf4)[(((size_t)(t + 1) * 256 + bid) * 32) * 4 + tid] = hv;
            } else {
                logits[((size_t)cb * Tt + t) * HH + j0 + cj] = hv;
            }
            if (t == Tt - 1) h_f[(size_t)cb * HH + j0 + cj] = hv;
            __threadfence();             // release h_t device-wide before barrier
        }

        // pipelined x-dot for step t+1 — fills the barrier-wait shadow
        if (t + 1 < Tt) {
#pragma unroll
            for (int r = 0; r < 8; ++r) xacc[r] = make_float4(0.f, 0.f, 0.f, 0.f);
            if (!GATHER) {
                dot32<32>(xT4 + (size_t)(t + 1) * 8192 + w * 1024 + b, wx, xacc);
            } else {
                dot32<1>((const float4*)(inputs + ((size_t)b * Tt + (t + 1)) * KI) + w * 32, wx, xacc);
            }
        }

        grid.sync();
    }
    if (tid < 128) c_f[(size_t)cb * HH + j0 + cj] = c_reg;
}

extern "C" void kernel_launch(void* const* d_in, const int* in_sizes, int n_in,
                              void* d_out, int out_size, void* d_ws, size_t ws_size,
                              hipStream_t stream)
{
    const float* inputs = (const float*)d_in[0];
    const float* h0     = (const float*)d_in[1];
    const float* c0     = (const float*)d_in[2];
    const float* W_ih   = (const float*)d_in[3];
    const float* b_ih   = (const float*)d_in[4];
    const float* W_hh   = (const float*)d_in[5];
    const float* b_hh   = (const float*)d_in[6];
    float* out = (float*)d_out;

    float4* xT4   = (float4*)d_ws;
    float4* hbuf4 = xT4 + (size_t)Tt * (KI / 4) * Bb;
    const size_t need = ((size_t)Tt * (KI / 4) * Bb + (size_t)(Tt + 1) * (HH / 4) * Bb) * sizeof(float4);

    const float4* xT4c = xT4;

    if (ws_size >= need) {
        prep_kernel<<<dim3(16416), dim3(256), 0, stream>>>((const float4*)inputs, h0, xT4, hbuf4);
        void (*k)(const float*, const float*, const float*, const float*, const float*,
                  const float*, const float*, const float4*, float4*, float*) = lstm_seq<false>;
        void* args[] = { (void*)&inputs, (void*)&h0, (void*)&c0, (void*)&W_ih, (void*)&b_ih,
                         (void*)&W_hh, (void*)&b_hh, (void*)&xT4c, (void*)&hbuf4, (void*)&out };
        hipLaunchCooperativeKernel((const void*)k, dim3(256), dim3(512), args, 0, stream);
        logits_kernel<<<dim3(16384), dim3(256), 0, stream>>>(hbuf4, (float4*)out);
    } else {
        void (*k)(const float*, const float*, const float*, const float*, const float*,
                  const float*, const float*, const float4*, float4*, float*) = lstm_seq<true>;
        void* args[] = { (void*)&inputs, (void*)&h0, (void*)&c0, (void*)&W_ih, (void*)&b_ih,
                         (void*)&W_hh, (void*)&b_hh, (void*)&xT4c, (void*)&hbuf4, (void*)&out };
        hipLaunchCooperativeKernel((const void*)k, dim3(256), dim3(512), args, 0, stream);
    }
}

// Round 5
// 19139.813 us; speedup vs baseline: 2.0077x; 2.0077x over previous
//
#include <hip/hip_runtime.h>
#include <hip/hip_cooperative_groups.h>

namespace cg = cooperative_groups;

constexpr int Bb = 32;     // batch
constexpr int Tt = 512;    // time
constexpr int KI = 1024;   // input dim
constexpr int HH = 1024;   // hidden dim

// ws layout (float4 units):
//   xT4  : [T][KI/4][B]   = 4,194,304 float4  (inputs transposed)
//   hbuf4: [T+1][HH/4][B] = 4,202,496 float4  (h history; slot 0 = h0)
//   bar  : 1 unsigned     (barrier counter, monotonic within a launch)

// ---- system-scope (cross-XCD coherent, cache-bypassing) ops ----
// Relaxed system atomics lower to global_load/store sc0 sc1 (bypass L1/L2,
// served at the device coherent point). NO fences -> L2 never invalidated:
// weights/xT4 stay cached across all 512 steps.
__device__ __forceinline__ void st_sys(float* p, float v) {
    __hip_atomic_store(p, v, __ATOMIC_RELAXED, __HIP_MEMORY_SCOPE_SYSTEM);
}
__device__ __forceinline__ unsigned long long ld_sys64(const unsigned long long* p) {
    return __hip_atomic_load(p, __ATOMIC_RELAXED, __HIP_MEMORY_SCOPE_SYSTEM);
}

// ---------------- prep: transpose inputs and h0 into lane-coalesced layout ----------------
__global__ void prep_kernel(const float4* __restrict__ in4,
                            const float* __restrict__ h0,
                            float4* __restrict__ xT4,
                            float4* __restrict__ hbuf4,
                            unsigned* bar)
{
    int idx = blockIdx.x * 256 + threadIdx.x;
    if (idx == 0) __hip_atomic_store(bar, 0u, __ATOMIC_RELAXED, __HIP_MEMORY_SCOPE_SYSTEM);
    constexpr int NX = Bb * Tt * (KI / 4);          // 4,194,304
    if (idx < NX) {
        int kq = idx & 255;
        int t  = (idx >> 8) & 511;
        int b  = idx >> 17;
        xT4[((size_t)t * 256 + kq) * 32 + b] = in4[idx];
    } else {
        int r = idx - NX;
        if (r < (HH / 4) * Bb) {                    // 8192
            int b  = r & 31;
            int jq = r >> 5;
            hbuf4[(size_t)jq * 32 + b] = *(const float4*)(h0 + (size_t)b * HH + jq * 4);
        }
    }
}

// ---------------- final: hbuf (transposed h history) -> logits [B][T][H] ----------------
__global__ void logits_kernel(const float4* __restrict__ hbuf4, float4* __restrict__ out4)
{
    int idx = blockIdx.x * 256 + threadIdx.x;       // (b*T + t)*256 + j4
    constexpr int N = Bb * Tt * (HH / 4);
    if (idx >= N) return;
    int j4 = idx & 255;
    int t  = (idx >> 8) & 511;
    int b  = idx >> 17;
    out4[idx] = hbuf4[((size_t)(t + 1) * 256 + j4) * 32 + b];
}

// 32-iter dot fragment, cached loads (x path, weights): 1 x-load + 8 w-loads -> 32 FMAs/iter
template<int STRIDE>
__device__ __forceinline__ void dot32(const float4* __restrict__ xp,
                                      const float4* const* __restrict__ wr,
                                      float4 acc[8])
{
#pragma unroll 4
    for (int i = 0; i < 32; ++i) {
        float4 xv = xp[(size_t)i * STRIDE];
#pragma unroll
        for (int r = 0; r < 8; ++r) {
            float4 wv = wr[r][i];
            acc[r].x = fmaf(wv.x, xv.x, acc[r].x);
            acc[r].y = fmaf(wv.y, xv.y, acc[r].y);
            acc[r].z = fmaf(wv.z, xv.z, acc[r].z);
            acc[r].w = fmaf(wv.w, xv.w, acc[r].w);
        }
    }
}

// h path: system-scope dwordx2 loads (bypass L1/L2 -> coherent point).
// hp = float4 slot (t*8192 + w*1024 + b) as float*; window stride 32 float4.
__device__ __forceinline__ void dot32_sys(const float* __restrict__ hp,
                                          const float4* const* __restrict__ wr,
                                          float4 acc[8])
{
#pragma unroll 8
    for (int i = 0; i < 32; ++i) {
        const unsigned long long* q = (const unsigned long long*)(hp + (size_t)i * 128);
        unsigned long long lo = ld_sys64(q);
        unsigned long long hi = ld_sys64(q + 1);
        float hx = __uint_as_float((unsigned)(lo & 0xffffffffull));
        float hy = __uint_as_float((unsigned)(lo >> 32));
        float hz = __uint_as_float((unsigned)(hi & 0xffffffffull));
        float hw = __uint_as_float((unsigned)(hi >> 32));
#pragma unroll
        for (int r = 0; r < 8; ++r) {
            float4 wv = wr[r][i];
            acc[r].x = fmaf(wv.x, hx, acc[r].x);
            acc[r].y = fmaf(wv.y, hy, acc[r].y);
            acc[r].z = fmaf(wv.z, hz, acc[r].z);
            acc[r].w = fmaf(wv.w, hw, acc[r].w);
        }
    }
}

// ---------------- persistent LSTM ----------------
// 256 blocks x 512 threads (8 waves = 2/SIMD), 1 block/CU. Block bid owns
// hidden units j in [bid*4, bid*4+4) -> 16 gate-rows. Wave w owns float4-k
// window [w*32, w*32+32) of both dots; lanes carry batch b; each half
// register-tiles 8 gate-rows. c lives in combiner registers (tid<128).
// Step schedule: hdot(t) -> publish -> combine + h-store(sys) -> drain ->
// ARRIVE (fire-and-forget) -> xdot(t+1) in barrier shadow -> spin -> sync.
// Barrier: monotonic system-scope counter; zero cache maintenance.
template<bool GATHER>
__global__ __launch_bounds__(512, 2)
void lstm_seq(const float* __restrict__ inputs,
              const float* __restrict__ h0,
              const float* __restrict__ c0,
              const float* __restrict__ W_ih,
              const float* __restrict__ b_ih,
              const float* __restrict__ W_hh,
              const float* __restrict__ b_hh,
              const float4* __restrict__ xT4,
              float4* __restrict__ hbuf4,
              unsigned* bar,
              float* __restrict__ out)
{
    cg::grid_group grid = cg::this_grid();
    const int tid  = threadIdx.x;
    const int bid  = blockIdx.x;
    const int w    = tid >> 6;           // wave 0..7 -> k-window
    const int lane = tid & 63;
    const int b    = lane & 31;          // batch on lanes (coalesced x/h reads)
    const int half = lane >> 5;          // half-wave -> row group
    const int j0   = bid * 4;

    // this thread's 8 gate-rows: rr = half*8 + r; global row = g*HH + j0 + jl
    // (g = rr&3: 0=i,1=f,2=o,3=g per reference row order; jl = rr>>2)
    const float4* wx[8];
    const float4* wh[8];
#pragma unroll
    for (int r = 0; r < 8; ++r) {
        int rr  = half * 8 + r;
        int row = (rr & 3) * HH + j0 + (rr >> 2);
        wx[r] = (const float4*)(W_ih + (size_t)row * KI) + w * 32;
        wh[r] = (const float4*)(W_hh + (size_t)row * HH) + w * 32;
    }

    __shared__ float part[16][8][33];    // [rr][wave][b]; padded: conflict-free combine

    // combiner: thread tid<128 owns (b=tid>>2, j=j0+(tid&3)); c never leaves regs
    const int cb = tid >> 2;
    const int cj = tid & 3;
    float c_reg = 0.f;
    float bsum[4] = {0.f, 0.f, 0.f, 0.f};
    if (tid < 128) {
        c_reg = c0[(size_t)cb * HH + j0 + cj];
#pragma unroll
        for (int g = 0; g < 4; ++g) {
            int row = g * HH + j0 + cj;
            bsum[g] = b_ih[row] + b_hh[row];
        }
    }

    float* logits = out;
    float* h_f = out + (size_t)Bb * Tt * HH;
    float* c_f = h_f + (size_t)Bb * HH;

    // prologue: xacc = xdot(t=0)
    float4 xacc[8];
#pragma unroll
    for (int r = 0; r < 8; ++r) xacc[r] = make_float4(0.f, 0.f, 0.f, 0.f);
    if (!GATHER) {
        dot32<32>(xT4 + (size_t)0 * 8192 + w * 1024 + b, wx, xacc);
    } else {
        dot32<1>((const float4*)(inputs + ((size_t)b * Tt + 0) * KI) + w * 32, wx, xacc);
    }

    for (int t = 0; t < Tt; ++t) {
        // h-dot for step t (h_{t-1} lives in slot t / logits row t-1)
        float4 hacc[8];
#pragma unroll
        for (int r = 0; r < 8; ++r) hacc[r] = make_float4(0.f, 0.f, 0.f, 0.f);
        if (!GATHER) {
            dot32_sys((const float*)(hbuf4 + (size_t)t * 8192 + w * 1024 + b), wh, hacc);
        } else {
            const float4* hp = (t == 0)
                ? (const float4*)(h0 + (size_t)b * HH) + w * 32
                : (const float4*)(logits + ((size_t)b * Tt + (t - 1)) * HH) + w * 32;
            dot32<1>(hp, wh, hacc);
        }

        // publish x+h partials
#pragma unroll
        for (int r = 0; r < 8; ++r) {
            float s = (hacc[r].x + hacc[r].y) + (hacc[r].z + hacc[r].w)
                    + (xacc[r].x + xacc[r].y) + (xacc[r].z + xacc[r].w);
            part[half * 8 + r][w][b] = s;
        }
        __syncthreads();

        if (tid < 128) {
            float pr[4];
#pragma unroll
            for (int g = 0; g < 4; ++g) {
                float s = bsum[g];
#pragma unroll
                for (int ww = 0; ww < 8; ++ww) s += part[cj * 4 + g][ww][cb];
                pr[g] = s;
            }
            float ig = 1.f / (1.f + expf(-pr[0]));
            float fg = 1.f / (1.f + expf(-pr[1]));
            float og = 1.f / (1.f + expf(-pr[2]));
            float gg = tanhf(pr[3]);
            c_reg = c_reg * fg + ig * gg;
            float hv = og * tanhf(c_reg);
            if (!GATHER) {
                // 128 consecutive floats of hbuf slot t+1, j-quad bid — written
                // through to the coherent point so any XCD can read next step
                st_sys((float*)hbuf4 + ((size_t)(t + 1) * 256 + bid) * 128 + tid, hv);
            } else {
                logits[((size_t)cb * Tt + t) * HH + j0 + cj] = hv;
            }
            if (t == Tt - 1) h_f[(size_t)cb * HH + j0 + cj] = hv;
        }

        if (!GATHER) {
            // drain this wave's vmem (h system-stores included)...
            asm volatile("s_waitcnt vmcnt(0)" ::: "memory");
            __syncthreads();                 // ...all waves' h-stores now at coherent point
            if (tid == 0) {
                // ARRIVE early, fire-and-forget (no response wait)
                __hip_atomic_fetch_add(bar, 1u, __ATOMIC_RELAXED, __HIP_MEMORY_SCOPE_SYSTEM);
            }
            // pipelined x-dot for step t+1 — fills the barrier-wait shadow
            if (t + 1 < Tt) {
#pragma unroll
                for (int r = 0; r < 8; ++r) xacc[r] = make_float4(0.f, 0.f, 0.f, 0.f);
                dot32<32>(xT4 + (size_t)(t + 1) * 8192 + w * 1024 + b, wx, xacc);
            }
            if (tid == 0) {
                unsigned target = (unsigned)(t + 1) * (unsigned)gridDim.x;
                while (__hip_atomic_load(bar, __ATOMIC_RELAXED, __HIP_MEMORY_SCOPE_SYSTEM) < target) {
                    __builtin_amdgcn_s_sleep(2);   // back off ~128 cyc: keep L3 line uncontended
                }
            }
            __syncthreads();
        } else {
            if (t + 1 < Tt) {
#pragma unroll
                for (int r = 0; r < 8; ++r) xacc[r] = make_float4(0.f, 0.f, 0.f, 0.f);
                dot32<1>((const float4*)(inputs + ((size_t)b * Tt + (t + 1)) * KI) + w * 32, wx, xacc);
            }
            if (tid < 128) __threadfence();
            grid.sync();
        }
    }
    if (tid < 128) c_f[(size_t)cb * HH + j0 + cj] = c_reg;
}

extern "C" void kernel_launch(void* const* d_in, const int* in_sizes, int n_in,
                              void* d_out, int out_size, void* d_ws, size_t ws_size,
                              hipStream_t stream)
{
    const float* inputs = (const float*)d_in[0];
    const float* h0     = (const float*)d_in[1];
    const float* c0     = (const float*)d_in[2];
    const float* W_ih   = (const float*)d_in[3];
    const float* b_ih   = (const float*)d_in[4];
    const float* W_hh   = (const float*)d_in[5];
    const float* b_hh   = (const float*)d_in[6];
    float* out = (float*)d_out;

    float4* xT4   = (float4*)d_ws;
    float4* hbuf4 = xT4 + (size_t)Tt * (KI / 4) * Bb;
    unsigned* bar = (unsigned*)(hbuf4 + (size_t)(Tt + 1) * (HH / 4) * Bb);
    const size_t need = ((size_t)Tt * (KI / 4) * Bb + (size_t)(Tt + 1) * (HH / 4) * Bb) * sizeof(float4) + 64;

    const float4* xT4c = xT4;

    if (ws_size >= need) {
        prep_kernel<<<dim3(16416), dim3(256), 0, stream>>>((const float4*)inputs, h0, xT4, hbuf4, bar);
        void (*k)(const float*, const float*, const float*, const float*, const float*,
                  const float*, const float*, const float4*, float4*, unsigned*, float*) = lstm_seq<false>;
        void* args[] = { (void*)&inputs, (void*)&h0, (void*)&c0, (void*)&W_ih, (void*)&b_ih,
                         (void*)&W_hh, (void*)&b_hh, (void*)&xT4c, (void*)&hbuf4, (void*)&bar, (void*)&out };
        hipLaunchCooperativeKernel((const void*)k, dim3(256), dim3(512), args, 0, stream);
        logits_kernel<<<dim3(16384), dim3(256), 0, stream>>>(hbuf4, (float4*)out);
    } else {
        void (*k)(const float*, const float*, const float*, const float*, const float*,
                  const float*, const float*, const float4*, float4*, unsigned*, float*) = lstm_seq<true>;
        void* args[] = { (void*)&inputs, (void*)&h0, (void*)&c0, (void*)&W_ih, (void*)&b_ih,
                         (void*)&W_hh, (void*)&b_hh, (void*)&xT4c, (void*)&hbuf4, (void*)&bar, (void*)&out };
        hipLaunchCooperativeKernel((const void*)k, dim3(256), dim3(512), args, 0, stream);
    }
}